// Round 4
// baseline (187.836 us; speedup 1.0000x reference)
//
#include <hip/hip_runtime.h>

#define BB 32
#define OO 64
#define II 64
#define FF 16
#define HH 128
#define WW 128

typedef __attribute__((ext_vector_type(8))) __bf16 bf16x8;
typedef __attribute__((ext_vector_type(4))) float f32x4;

// padded, channel-minor x: [bc][130][130][64] bf16 (1-px zero halo)
#define XROW 130
#define XB ((size_t)XROW * XROW * 64)

typedef __attribute__((address_space(3))) uint8_t  lds_u8;
typedef __attribute__((address_space(1))) const uint8_t g_u8;

// ---------------- Kernel 1: weight/bias generation ----------------
__global__ __launch_bounds__(64)
void gen_weights(const float* __restrict__ addr,
                 const float* __restrict__ w_bank,
                 const float* __restrict__ b_bank,
                 __bf16* __restrict__ wT,
                 float* __restrict__ bias_out) {
    const int bo  = blockIdx.x;            // b*64 + o
    const int tid = threadIdx.x;           // i = 0..63

    __shared__ float bank_s[FF * 9];
    __shared__ float bbank_s[FF];
    for (int idx = tid; idx < FF * 9; idx += 64) bank_s[idx] = w_bank[idx];
    if (tid < FF) bbank_s[tid] = b_bank[tid];
    __syncthreads();

    const float* arow = addr + ((size_t)bo * (II + 1) + 1 + tid) * FF;
    float a[FF];
    float m = -1e30f;
#pragma unroll
    for (int f = 0; f < FF; ++f) { a[f] = arow[f]; m = fmaxf(m, a[f]); }
    float s = 0.f;
#pragma unroll
    for (int f = 0; f < FF; ++f) { a[f] = __expf(a[f] - m); s += a[f]; }
    const float inv = 1.0f / s;

    const int b = bo >> 6, o = bo & 63;
#pragma unroll
    for (int kl = 0; kl < 9; ++kl) {
        float acc = 0.f;
#pragma unroll
        for (int f = 0; f < FF; ++f) acc += a[f] * bank_s[f * 9 + kl];
        wT[(((size_t)b * 9 + kl) * OO + o) * II + tid] = (__bf16)(acc * inv);
    }

    if (tid == 0) {
        const float* brow = addr + (size_t)bo * (II + 1) * FF;
        float bb[FF];
        float bm = -1e30f;
#pragma unroll
        for (int f = 0; f < FF; ++f) { bb[f] = brow[f]; bm = fmaxf(bm, bb[f]); }
        float bs = 0.f;
#pragma unroll
        for (int f = 0; f < FF; ++f) { bb[f] = __expf(bb[f] - bm); bs += bb[f]; }
        float acc = 0.f;
#pragma unroll
        for (int f = 0; f < FF; ++f) acc += bb[f] * bbank_s[f];
        bias_out[bo] = acc / bs;
    }
}

// ---------------- Kernel 2: transpose + pad + bf16 cast (float4 loads) ----------------
__global__ __launch_bounds__(256)
void transpose_pad(const float* __restrict__ x, __bf16* __restrict__ xTp, int b0) {
    const int ph = blockIdx.x;             // 0..129 padded row
    const int bc = blockIdx.y;
    const int t  = threadIdx.x;
    __bf16* dst = xTp + (size_t)bc * XB + (size_t)ph * (XROW * 64);

    if (ph == 0 || ph == XROW - 1) {       // top/bottom zero rows
        uint4 z = {0, 0, 0, 0};
        uint4* d4 = (uint4*)dst;
        for (int idx = t; idx < 1040; idx += 256) d4[idx] = z;
        return;
    }
    if (t < 16) {                          // left/right zero columns
        uint4 z = {0, 0, 0, 0};
        const int px = (t >> 3) ? (XROW - 1) : 0;
        ((uint4*)(dst + px * 64))[t & 7] = z;
    }

    const int h = ph - 1;
    const int b = b0 + bc;
    const int px0 = (t >> 3) * 4;          // 0,4,...,124
    const int i0  = (t & 7) * 8;           // 0,8,...,56
    const float* xs = x + (((size_t)b * II + i0) * HH + h) * WW + px0;

    float4 v[8];
#pragma unroll
    for (int j = 0; j < 8; ++j)
        v[j] = *(const float4*)(xs + (size_t)j * (HH * WW));

#pragma unroll
    for (int p = 0; p < 4; ++p) {
        __bf16 u[8];
#pragma unroll
        for (int j = 0; j < 8; ++j)
            u[j] = (__bf16)(((const float*)&v[j])[p]);
        *(uint4*)(dst + (px0 + 1 + p) * 64 + i0) = *(const uint4*)u;
    }
}

// ---------------- Kernel 3: LDS-staged implicit-GEMM conv via MFMA ----------------
// Block: 2 output rows x 64 px (half) x 64 o. 4 waves: (row, 32-px quarter).
// LDS: 4 padded rows x 66 px, chunk-XOR swizzled -> conflict-free ds_read_b128.
#define PXW 66
#define NCHK 8
#define ROWCHK (PXW * NCHK)       // 528
#define TOTCHK (4 * ROWCHK)       // 2112 chunks = 33792 B

__global__ __launch_bounds__(256, 4)
void conv_mfma(const __bf16* __restrict__ xTp, const __bf16* __restrict__ wT,
               const float* __restrict__ bias, float* __restrict__ y,
               int b0, int nb) {
    // bijective XCD swizzle: consecutive work ids land on one XCD
    const int nwg = 128 * nb;
    const int cpx = nwg >> 3;
    const int hwid = blockIdx.x;
    const int work = (hwid & 7) * cpx + (hwid >> 3);
    const int bc   = work >> 7;            // batch within chunk
    const int r7   = work & 127;
    const int hb   = r7 >> 1;              // row-pair 0..63
    const int pwb  = (r7 & 1) * 64;        // px half base
    const int b    = b0 + bc;

    const int t  = threadIdx.x;
    const int wv = t >> 6;
    const int l  = t & 63;
    const int lm = l & 15;
    const int lk = l >> 4;
    const int lrw = wv >> 1;               // output row within pair
    const int pxb = (wv & 1) * 32;         // wave's px quarter base
    const int row = hb * 2 + lrw;

    __shared__ __bf16 xs[TOTCHK * 8];      // 33792 B

    // ---- stage 4 padded rows x 66 px of xTp into LDS, source-swizzled ----
    const __bf16* xbase = xTp + (size_t)bc * XB + ((size_t)(hb * 2) * XROW + pwb) * 64;
#pragma unroll
    for (int it = 0; it < 9; ++it) {
        const int gbase = it * 256 + (t & 192);        // wave-uniform chunk base
        if (gbase < TOTCHK) {
            const int cid = it * 256 + t;
            const int lr  = cid / ROWCHK;
            const int rem = cid - lr * ROWCHK;
            const int lpx = rem >> 3;
            const int cc  = (rem & 7) ^ (lpx & 7);     // inverse-swizzled source chunk
            const __bf16* src = xbase + ((size_t)lr * XROW + lpx) * 64 + cc * 8;
            __builtin_amdgcn_global_load_lds((g_u8*)src,
                                             (lds_u8*)&xs[(size_t)gbase * 8],
                                             16, 0, 0);
        }
    }

    // bias -> acc init (overlaps staging)
    f32x4 acc[4][2];
    {
        const float* bp = bias + b * OO;
#pragma unroll
        for (int mf = 0; mf < 4; ++mf) {
            f32x4 bv;
#pragma unroll
            for (int r = 0; r < 4; ++r) bv[r] = bp[mf * 16 + lk * 4 + r];
#pragma unroll
            for (int nf = 0; nf < 2; ++nf) acc[mf][nf] = bv;
        }
    }

    // A prefetch for k-step 0
    const __bf16* wb  = wT + (size_t)b * 9 * OO * II;
    const __bf16* wk0 = wb + lm * II + lk * 8;
    bf16x8 A[2][4];
#pragma unroll
    for (int mf = 0; mf < 4; ++mf)
        A[0][mf] = *(const bf16x8*)(wk0 + mf * 16 * II);

    __syncthreads();   // staging complete

    const char* xsb = (const char*)xs;

    // 18 flattened k-steps: ks -> (kl = ks>>1, k0i = ks&1)
#pragma unroll
    for (int ks = 0; ks < 18; ++ks) {
        const int kl  = ks >> 1;
        const int k0i = ks & 1;
        const int cur = ks & 1, nxt = cur ^ 1;
        if (ks < 17) {                      // prefetch A for ks+1
            const int kl2 = (ks + 1) >> 1, k02 = (ks + 1) & 1;
            const __bf16* wk = wk0 + kl2 * (OO * II) + k02 * 32;
#pragma unroll
            for (int mf = 0; mf < 4; ++mf)
                A[nxt][mf] = *(const bf16x8*)(wk + mf * 16 * II);
        }
        const int dr = kl / 3, dc = kl - dr * 3;
        const int lrb = (lrw + dr) * PXW;
        const int cc  = lk + 4 * k0i;
        bf16x8 bv[2];
#pragma unroll
        for (int nf = 0; nf < 2; ++nf) {
            const int lpx = pxb + nf * 16 + lm + dc;
            const int addr = (((lrb + lpx) << 3) + (cc ^ (lpx & 7))) << 4;
            bv[nf] = *(const bf16x8*)(xsb + addr);
        }
        __builtin_amdgcn_s_setprio(1);
#pragma unroll
        for (int mf = 0; mf < 4; ++mf)
#pragma unroll
            for (int nf = 0; nf < 2; ++nf)
                acc[mf][nf] = __builtin_amdgcn_mfma_f32_16x16x32_bf16(
                    A[cur][mf], bv[nf], acc[mf][nf], 0, 0, 0);
        __builtin_amdgcn_s_setprio(0);
    }

    // epilogue: D row=(lk*4+r)+16*mf -> o ; col=lm -> px
#pragma unroll
    for (int mf = 0; mf < 4; ++mf)
#pragma unroll
        for (int r = 0; r < 4; ++r) {
            const int o = mf * 16 + lk * 4 + r;
            float* yo = y + (((size_t)b * OO + o) * HH + row) * WW + pwb + pxb;
#pragma unroll
            for (int nf = 0; nf < 2; ++nf)
                yo[nf * 16 + lm] = acc[mf][nf][r];
        }
}

extern "C" void kernel_launch(void* const* d_in, const int* in_sizes, int n_in,
                              void* d_out, int out_size, void* d_ws, size_t ws_size,
                              hipStream_t stream) {
    const float* addresses = (const float*)d_in[0];   // (B,O,I+1,F)
    const float* x         = (const float*)d_in[1];   // (B,I,H,W)
    const float* w_bank    = (const float*)d_in[2];   // (F,3,3)
    const float* b_bank    = (const float*)d_in[3];   // (F,)
    float* out = (float*)d_out;                       // (B,O,H,W)

    // ws layout: [bias 8KB][wT 2.25MB][xTp chunk]
    float*  bias_ws = (float*)d_ws;
    __bf16* wT      = (__bf16*)((char*)d_ws + 8192);
    const size_t wT_bytes = (size_t)BB * 9 * OO * II * 2;
    __bf16* xTp     = (__bf16*)((char*)d_ws + 8192 + wT_bytes);
    const size_t fixed = 8192 + wT_bytes;
    const size_t xcap  = (ws_size > fixed) ? ws_size - fixed : 0;

    int nb = BB;
    while (nb > 1 && (size_t)nb * XB * 2 > xcap) nb >>= 1;

    gen_weights<<<BB * OO, 64, 0, stream>>>(addresses, w_bank, b_bank, wT, bias_ws);

    for (int b0 = 0; b0 < BB; b0 += nb) {
        dim3 gt(XROW, nb);
        transpose_pad<<<gt, 256, 0, stream>>>(x, xTp, b0);
        conv_mfma<<<128 * nb, 256, 0, stream>>>(xTp, wT, bias_ws, out, b0, nb);
    }
}

// Round 5
// 97.354 us; speedup vs baseline: 1.9294x; 1.9294x over previous
//
#include <hip/hip_runtime.h>

#define BB 32
#define OO 64
#define II 64
#define FF 16
#define HH 128
#define WW 128

typedef __attribute__((ext_vector_type(8))) __bf16 bf16x8;
typedef __attribute__((ext_vector_type(4))) float f32x4;

// padded, channel-minor x: [bc][130][130][64] bf16 (1-px zero halo)
#define XROW 130
#define XB ((size_t)XROW * XROW * 64)

typedef __attribute__((address_space(3))) uint8_t  lds_u8;
typedef __attribute__((address_space(1))) const uint8_t g_u8;

// ---------------- Kernel 1: weight/bias generation ----------------
__global__ __launch_bounds__(64)
void gen_weights(const float* __restrict__ addr,
                 const float* __restrict__ w_bank,
                 const float* __restrict__ b_bank,
                 __bf16* __restrict__ wT,
                 float* __restrict__ bias_out) {
    const int bo  = blockIdx.x;            // b*64 + o
    const int tid = threadIdx.x;           // i = 0..63

    __shared__ float bank_s[FF * 9];
    __shared__ float bbank_s[FF];
    for (int idx = tid; idx < FF * 9; idx += 64) bank_s[idx] = w_bank[idx];
    if (tid < FF) bbank_s[tid] = b_bank[tid];
    __syncthreads();

    const float* arow = addr + ((size_t)bo * (II + 1) + 1 + tid) * FF;
    float a[FF];
    float m = -1e30f;
#pragma unroll
    for (int f = 0; f < FF; ++f) { a[f] = arow[f]; m = fmaxf(m, a[f]); }
    float s = 0.f;
#pragma unroll
    for (int f = 0; f < FF; ++f) { a[f] = __expf(a[f] - m); s += a[f]; }
    const float inv = 1.0f / s;

    const int b = bo >> 6, o = bo & 63;
#pragma unroll
    for (int kl = 0; kl < 9; ++kl) {
        float acc = 0.f;
#pragma unroll
        for (int f = 0; f < FF; ++f) acc += a[f] * bank_s[f * 9 + kl];
        wT[(((size_t)b * 9 + kl) * OO + o) * II + tid] = (__bf16)(acc * inv);
    }

    if (tid == 0) {
        const float* brow = addr + (size_t)bo * (II + 1) * FF;
        float bb[FF];
        float bm = -1e30f;
#pragma unroll
        for (int f = 0; f < FF; ++f) { bb[f] = brow[f]; bm = fmaxf(bm, bb[f]); }
        float bs = 0.f;
#pragma unroll
        for (int f = 0; f < FF; ++f) { bb[f] = __expf(bb[f] - bm); bs += bb[f]; }
        float acc = 0.f;
#pragma unroll
        for (int f = 0; f < FF; ++f) acc += bb[f] * bbank_s[f];
        bias_out[bo] = acc / bs;
    }
}

// ---------------- Kernel 2: transpose + pad + bf16 cast (float4 loads) ----------------
__global__ __launch_bounds__(256)
void transpose_pad(const float* __restrict__ x, __bf16* __restrict__ xTp, int b0) {
    const int ph = blockIdx.x;             // 0..129 padded row
    const int bc = blockIdx.y;
    const int t  = threadIdx.x;
    __bf16* dst = xTp + (size_t)bc * XB + (size_t)ph * (XROW * 64);

    if (ph == 0 || ph == XROW - 1) {       // top/bottom zero rows
        uint4 z = {0, 0, 0, 0};
        uint4* d4 = (uint4*)dst;
        for (int idx = t; idx < 1040; idx += 256) d4[idx] = z;
        return;
    }
    if (t < 16) {                          // left/right zero columns
        uint4 z = {0, 0, 0, 0};
        const int px = (t >> 3) ? (XROW - 1) : 0;
        ((uint4*)(dst + px * 64))[t & 7] = z;
    }

    const int h = ph - 1;
    const int b = b0 + bc;
    const int px0 = (t >> 3) * 4;          // 0,4,...,124
    const int i0  = (t & 7) * 8;           // 0,8,...,56
    const float* xs = x + (((size_t)b * II + i0) * HH + h) * WW + px0;

    float4 v[8];
#pragma unroll
    for (int j = 0; j < 8; ++j)
        v[j] = *(const float4*)(xs + (size_t)j * (HH * WW));

#pragma unroll
    for (int p = 0; p < 4; ++p) {
        __bf16 u[8];
#pragma unroll
        for (int j = 0; j < 8; ++j)
            u[j] = (__bf16)(((const float*)&v[j])[p]);
        *(uint4*)(dst + (px0 + 1 + p) * 64 + i0) = *(const uint4*)u;
    }
}

// ---------------- Kernel 3: all-LDS implicit-GEMM conv ----------------
// 512 threads (8 waves), 1 block/CU (140KB LDS). Grid = 8*nb blocks.
// Block: (b, px-half, 32-row group). 16 phases of {2 rows x 64 px x 64 o}.
// A (weights, 72KB) staged in LDS once; x rows in 8-slot mod-8 ring,
// 2 rows prefetched per phase via global_load_lds (T3-minimum pipeline).
#define SLOTB 8704               // 68 px * 128 B (padded for wave-aligned staging)
#define RINGOFF 73728            // A region = [0, 73728)
#define LDSZ (RINGOFF + 8 * SLOTB)   // 143360 B

// stage padded rows r_, r_+1 (r_ even) into ring slots (r_&7, r_&7+1)
#define STAGE_PAIR(r_) do {                                                        \
    const int sb_ = ((r_) & 7) * SLOTB;                                            \
    _Pragma("unroll")                                                              \
    for (int it_ = 0; it_ < 3; ++it_) {                                            \
        const int gb_ = it_ * 512 + (t & 448);     /* wave-uniform */              \
        if (gb_ < 1088) {                          /* 17 waves exactly */          \
            const int cid_ = it_ * 512 + t;                                        \
            const int lr_  = (cid_ >= 544) ? 1 : 0;                                \
            const int wi_  = cid_ - 544 * lr_;                                     \
            const int px_  = wi_ >> 3;             /* 0..67 */                     \
            const int c_   = wi_ & 7;                                              \
            int spx_ = 64 * ph + px_; if (spx_ > 129) spx_ = 129;                  \
            const __bf16* s_ = xb + (size_t)((r_) + lr_) * (XROW * 64)             \
                               + spx_ * 64 + ((c_ ^ (px_ & 7)) << 3);              \
            __builtin_amdgcn_global_load_lds((g_u8*)s_,                            \
                (lds_u8*)(LDS + RINGOFF + sb_ + (size_t)gb_ * 16), 16, 0, 0);      \
        }                                                                          \
    }                                                                              \
} while (0)

__global__ __launch_bounds__(512, 2)
void conv_mfma(const __bf16* __restrict__ xTp, const __bf16* __restrict__ wT,
               const float* __restrict__ bias, float* __restrict__ y,
               int b0, int nb) {
    __shared__ __align__(16) char LDS[LDSZ];

    // bijective XCD swizzle: consecutive work ids share a batch -> one XCD
    const int nwg = 8 * nb;
    const int cpx = nwg >> 3;
    const int hwid = blockIdx.x;
    const int work = (hwid & 7) * cpx + (hwid >> 3);
    const int bc = work >> 3;
    const int r3 = work & 7;
    const int ph = r3 >> 2;                // px half (64 px)
    const int rg = r3 & 3;                 // 32-row group
    const int b  = b0 + bc;
    const int R0 = rg * 32;

    const int t  = threadIdx.x;
    const int w  = t >> 6;
    const int l  = t & 63;
    const int lm = l & 15;
    const int lk = l >> 4;
    const int oh = w >> 2;                 // o half (32 o)
    const int g  = w & 3;                  // px-16 group within 64

    const __bf16* xb = xTp + (size_t)bc * XB;
    const __bf16* wb = wT + (size_t)b * 9 * OO * II;

    // ---- prologue: stage A (4608 chunks, source-swizzled) ----
#pragma unroll
    for (int it = 0; it < 9; ++it) {
        const int cid = it * 512 + t;
        const int kl  = cid >> 9;
        const int rem = cid & 511;
        const int o   = rem >> 3;
        const int c   = rem & 7;
        const __bf16* src = wb + ((kl * 64 + o) << 6) + ((c ^ (o & 7)) << 3);
        __builtin_amdgcn_global_load_lds((g_u8*)src,
            (lds_u8*)(LDS + (size_t)(it * 512 + (t & 448)) * 16), 16, 0, 0);
    }
    // stage x padded rows R0..R0+3
    STAGE_PAIR(R0);
    STAGE_PAIR(R0 + 2);

    // bias preload (overlaps staging)
    float bbias[2][4];
    {
        const float* bp = bias + b * OO;
#pragma unroll
        for (int mf = 0; mf < 2; ++mf)
#pragma unroll
            for (int r = 0; r < 4; ++r)
                bbias[mf][r] = bp[oh * 32 + mf * 16 + lk * 4 + r];
    }
    f32x4 acc[2][2];
#pragma unroll
    for (int mf = 0; mf < 2; ++mf)
#pragma unroll
        for (int nf = 0; nf < 2; ++nf)
#pragma unroll
            for (int r = 0; r < 4; ++r)
                acc[mf][nf][r] = bbias[mf][r];

    __syncthreads();                       // staging landed

    const int pxbase = g * 16 + lm;        // lane's local px (0..63)
    const int obase0 = oh * 32 + lm;       // lane's A row for mf=0
    int s0 = 0;                            // (2p) & 7

    for (int p = 0; p < 16; ++p) {
        if (p < 15) STAGE_PAIR(R0 + 2 * p + 4);   // prefetch next phase's rows

#pragma unroll
        for (int ks = 0; ks < 18; ++ks) {
            const int kl = ks >> 1, k0 = ks & 1;
            const int dr = kl / 3, dc = kl - 3 * dr;
            const int cc = lk + 4 * k0;    // logical 16B chunk of the k-slice
            bf16x8 af[2], bv[2];
#pragma unroll
            for (int mf = 0; mf < 2; ++mf) {
                const int aaddr = kl * 8192 + (obase0 + mf * 16) * 128
                                + ((cc ^ (lm & 7)) << 4);
                af[mf] = *(const bf16x8*)(LDS + aaddr);
            }
            const int lpx = pxbase + dc;
#pragma unroll
            for (int nf = 0; nf < 2; ++nf) {
                const int slot = (s0 + nf + dr) & 7;
                const int baddr = RINGOFF + slot * SLOTB + lpx * 128
                                + ((cc ^ (lpx & 7)) << 4);
                bv[nf] = *(const bf16x8*)(LDS + baddr);
            }
#pragma unroll
            for (int mf = 0; mf < 2; ++mf)
#pragma unroll
                for (int nf = 0; nf < 2; ++nf)
                    acc[mf][nf] = __builtin_amdgcn_mfma_f32_16x16x32_bf16(
                        af[mf], bv[nf], acc[mf][nf], 0, 0, 0);
        }

        __syncthreads();                   // drains prefetch; ring safe to rotate

        // stores (global only; overlap next phase) + acc reinit
#pragma unroll
        for (int mf = 0; mf < 2; ++mf)
#pragma unroll
            for (int r = 0; r < 4; ++r) {
                const int o = oh * 32 + mf * 16 + lk * 4 + r;
#pragma unroll
                for (int nf = 0; nf < 2; ++nf) {
                    const int rowg = R0 + 2 * p + nf;
                    y[(((size_t)b * OO + o) * HH + rowg) * WW + ph * 64 + pxbase]
                        = acc[mf][nf][r];
                }
            }
#pragma unroll
        for (int mf = 0; mf < 2; ++mf)
#pragma unroll
            for (int nf = 0; nf < 2; ++nf)
#pragma unroll
                for (int r = 0; r < 4; ++r)
                    acc[mf][nf][r] = bbias[mf][r];

        s0 = (s0 + 2) & 7;
    }
}

extern "C" void kernel_launch(void* const* d_in, const int* in_sizes, int n_in,
                              void* d_out, int out_size, void* d_ws, size_t ws_size,
                              hipStream_t stream) {
    const float* addresses = (const float*)d_in[0];   // (B,O,I+1,F)
    const float* x         = (const float*)d_in[1];   // (B,I,H,W)
    const float* w_bank    = (const float*)d_in[2];   // (F,3,3)
    const float* b_bank    = (const float*)d_in[3];   // (F,)
    float* out = (float*)d_out;                       // (B,O,H,W)

    // ws layout: [bias 8KB][wT 2.25MB][xTp chunk]
    float*  bias_ws = (float*)d_ws;
    __bf16* wT      = (__bf16*)((char*)d_ws + 8192);
    const size_t wT_bytes = (size_t)BB * 9 * OO * II * 2;
    __bf16* xTp     = (__bf16*)((char*)d_ws + 8192 + wT_bytes);
    const size_t fixed = 8192 + wT_bytes;
    const size_t xcap  = (ws_size > fixed) ? ws_size - fixed : 0;

    int nb = BB;
    while (nb > 1 && (size_t)nb * XB * 2 > xcap) nb >>= 1;

    gen_weights<<<BB * OO, 64, 0, stream>>>(addresses, w_bank, b_bank, wT, bias_ws);

    for (int b0 = 0; b0 < BB; b0 += nb) {
        dim3 gt(XROW, nb);
        transpose_pad<<<gt, 256, 0, stream>>>(x, xTp, b0);
        conv_mfma<<<8 * nb, 512, 0, stream>>>(xTp, wT, bias_ws, out, b0, nb);
    }
}

// Round 6
// 77.299 us; speedup vs baseline: 2.4300x; 1.2594x over previous
//
#include <hip/hip_runtime.h>

#define BB 32
#define OO 64
#define II 64
#define FF 16
#define HH 128
#define WW 128

typedef __attribute__((ext_vector_type(8))) __bf16 bf16x8;
typedef __attribute__((ext_vector_type(4))) float f32x4;

typedef __attribute__((address_space(3))) uint8_t  lds_u8;
typedef __attribute__((address_space(1))) const uint8_t g_u8;

// ---------------- Kernel 1: weight/bias generation ----------------
__global__ __launch_bounds__(64)
void gen_weights(const float* __restrict__ addr,
                 const float* __restrict__ w_bank,
                 const float* __restrict__ b_bank,
                 __bf16* __restrict__ wT,
                 float* __restrict__ bias_out) {
    const int bo  = blockIdx.x;            // b*64 + o
    const int tid = threadIdx.x;           // i = 0..63

    __shared__ float bank_s[FF * 9];
    __shared__ float bbank_s[FF];
    for (int idx = tid; idx < FF * 9; idx += 64) bank_s[idx] = w_bank[idx];
    if (tid < FF) bbank_s[tid] = b_bank[tid];
    __syncthreads();

    const float* arow = addr + ((size_t)bo * (II + 1) + 1 + tid) * FF;
    float a[FF];
    float m = -1e30f;
#pragma unroll
    for (int f = 0; f < FF; ++f) { a[f] = arow[f]; m = fmaxf(m, a[f]); }
    float s = 0.f;
#pragma unroll
    for (int f = 0; f < FF; ++f) { a[f] = __expf(a[f] - m); s += a[f]; }
    const float inv = 1.0f / s;

    const int b = bo >> 6, o = bo & 63;
#pragma unroll
    for (int kl = 0; kl < 9; ++kl) {
        float acc = 0.f;
#pragma unroll
        for (int f = 0; f < FF; ++f) acc += a[f] * bank_s[f * 9 + kl];
        wT[(((size_t)b * 9 + kl) * OO + o) * II + tid] = (__bf16)(acc * inv);
    }

    if (tid == 0) {
        const float* brow = addr + (size_t)bo * (II + 1) * FF;
        float bb[FF];
        float bm = -1e30f;
#pragma unroll
        for (int f = 0; f < FF; ++f) { bb[f] = brow[f]; bm = fmaxf(bm, bb[f]); }
        float bs = 0.f;
#pragma unroll
        for (int f = 0; f < FF; ++f) { bb[f] = __expf(bb[f] - bm); bs += bb[f]; }
        float acc = 0.f;
#pragma unroll
        for (int f = 0; f < FF; ++f) acc += bb[f] * bbank_s[f];
        bias_out[bo] = acc / bs;
    }
}

// ---------------- Kernel 2: fused transpose + implicit-GEMM conv ----------------
// 512 threads (8 waves), 1 block/CU (138KB LDS). Grid = 256 blocks (1/CU).
// Block: (b, px-half, 32-row group). 16 phases of {2 rows x 64 px x 64 o}.
// A (72KB) staged via global_load_lds once. x staged straight from raw fp32 x:
// issue coalesced loads at phase start -> MFMA -> cvt bf16 + swizzled ds_write
// into 8-slot ring (T14 async split). Padding handled by load predicates.
#define SLOTB 8448               // 66 px * 128 B
#define RINGOFF 73728            // A region = [0, 73728)
#define LDSZ (RINGOFF + 8 * SLOTB)   // 141312 B

// issue loads for ring pair q (padded local rows 2q, 2q+1) into sm0/sm1/smt
#define LOADPAIR(q_) do {                                                          \
    const int pxg_ = ph * 64 + l - 1;                                              \
    const bool okpx_ = (unsigned)pxg_ < 128u;                                      \
    _Pragma("unroll")                                                              \
    for (int j_ = 0; j_ < 2; ++j_) {                                               \
        const int rr_ = R0 + 2 * (q_) + j_ - 1;                                    \
        const bool ok_ = okpx_ && ((unsigned)rr_ < 128u);                          \
        const float* xs_ = xb + ((size_t)(wv * 8) * HH + rr_) * WW + pxg_;         \
        float* dst_ = j_ ? sm1 : sm0;                                              \
        _Pragma("unroll")                                                          \
        for (int jj_ = 0; jj_ < 8; ++jj_) {                                        \
            float v_ = 0.f;                                                        \
            if (ok_) v_ = xs_[(size_t)jj_ * (HH * WW)];                            \
            dst_[jj_] = v_;                                                        \
        }                                                                          \
    }                                                                              \
    {   /* tail: px 64,65 for all 16 (row,cc) combos, lanes 0..31 of wave 0 */     \
        const int lr_ = l >> 4;                                                    \
        const int cc_ = (l >> 1) & 7;                                              \
        const int pxl_ = 64 + (l & 1);                                             \
        const int pxg2_ = ph * 64 + pxl_ - 1;                                      \
        const int rr_ = R0 + 2 * (q_) + lr_ - 1;                                   \
        const bool ok_ = (t < 32) && ((unsigned)pxg2_ < 128u)                      \
                         && ((unsigned)rr_ < 128u);                                \
        const float* xs_ = xb + ((size_t)(cc_ * 8) * HH + rr_) * WW + pxg2_;       \
        _Pragma("unroll")                                                          \
        for (int jj_ = 0; jj_ < 8; ++jj_) {                                        \
            float v_ = 0.f;                                                        \
            if (ok_) v_ = xs_[(size_t)jj_ * (HH * WW)];                            \
            smt[jj_] = v_;                                                         \
        }                                                                          \
    }                                                                              \
} while (0)

// convert + ds_write pair q (implicit vmcnt wait on sm* uses)
#define WRITEPAIR(q_) do {                                                         \
    bf16x8 u_;                                                                     \
    _Pragma("unroll")                                                              \
    for (int jj_ = 0; jj_ < 8; ++jj_) u_[jj_] = (__bf16)sm0[jj_];                  \
    *(bf16x8*)(LDS + RINGOFF + ((2 * (q_)) & 7) * SLOTB + l * 128                  \
               + ((wv ^ (l & 7)) << 4)) = u_;                                      \
    _Pragma("unroll")                                                              \
    for (int jj_ = 0; jj_ < 8; ++jj_) u_[jj_] = (__bf16)sm1[jj_];                  \
    *(bf16x8*)(LDS + RINGOFF + ((2 * (q_) + 1) & 7) * SLOTB + l * 128              \
               + ((wv ^ (l & 7)) << 4)) = u_;                                      \
    if (t < 32) {                                                                  \
        const int lr_ = l >> 4;                                                    \
        const int cc_ = (l >> 1) & 7;                                              \
        const int pxl_ = 64 + (l & 1);                                             \
        _Pragma("unroll")                                                          \
        for (int jj_ = 0; jj_ < 8; ++jj_) u_[jj_] = (__bf16)smt[jj_];              \
        *(bf16x8*)(LDS + RINGOFF + ((2 * (q_) + lr_) & 7) * SLOTB + pxl_ * 128     \
                   + ((cc_ ^ (pxl_ & 7)) << 4)) = u_;                              \
    }                                                                              \
} while (0)

__global__ __launch_bounds__(512, 2)
void conv_fused(const float* __restrict__ x, const __bf16* __restrict__ wT,
                const float* __restrict__ bias, float* __restrict__ y) {
    __shared__ __align__(16) char LDS[LDSZ];

    // bijective XCD swizzle: blocks of one batch share an XCD
    const int hwid = blockIdx.x;
    const int work = (hwid & 7) * 32 + (hwid >> 3);
    const int b  = work >> 3;
    const int r3 = work & 7;
    const int ph = r3 >> 2;                // px half (64 px)
    const int rg = r3 & 3;                 // 32-row group
    const int R0 = rg * 32;

    const int t  = threadIdx.x;
    const int wv = t >> 6;
    const int l  = t & 63;
    const int lm = l & 15;
    const int lk = l >> 4;
    const int oh = wv >> 2;                // o half (32 o)
    const int g  = wv & 3;                 // px-16 group within 64

    const __bf16* wb = wT + (size_t)b * 9 * OO * II;
    const float*  xb = x + (size_t)b * II * HH * WW;

    // ---- prologue: stage A (4608 chunks, source-swizzled) ----
#pragma unroll
    for (int it = 0; it < 9; ++it) {
        const int cid = it * 512 + t;
        const int kl  = cid >> 9;
        const int rem = cid & 511;
        const int o   = rem >> 3;
        const int c   = rem & 7;
        const __bf16* src = wb + ((kl * 64 + o) << 6) + ((c ^ (o & 7)) << 3);
        __builtin_amdgcn_global_load_lds((g_u8*)src,
            (lds_u8*)(LDS + (size_t)(it * 512 + (t & 448)) * 16), 16, 0, 0);
    }

    float sm0[8], sm1[8], smt[8];

    // stage x ring pairs 0,1 (padded local rows 0..3)
    LOADPAIR(0);
    WRITEPAIR(0);
    LOADPAIR(1);
    WRITEPAIR(1);

    // bias preload
    float bbias[2][4];
    {
        const float* bp = bias + b * OO;
#pragma unroll
        for (int mf = 0; mf < 2; ++mf)
#pragma unroll
            for (int r = 0; r < 4; ++r)
                bbias[mf][r] = bp[oh * 32 + mf * 16 + lk * 4 + r];
    }
    f32x4 acc[2][2];
#pragma unroll
    for (int mf = 0; mf < 2; ++mf)
#pragma unroll
        for (int nf = 0; nf < 2; ++nf)
#pragma unroll
            for (int r = 0; r < 4; ++r)
                acc[mf][nf][r] = bbias[mf][r];

    __syncthreads();                       // A + ring pairs 0,1 landed

    const int pxbase = g * 16 + lm;        // lane's local px (0..63)
    const int obase0 = oh * 32 + lm;       // lane's A row for mf=0
    int s0 = 0;                            // slot base = (2p) & 7

    for (int p = 0; p < 16; ++p) {
        if (p < 15) LOADPAIR(p + 2);       // issue next pair's global loads

#pragma unroll
        for (int ks = 0; ks < 18; ++ks) {
            const int kl = ks >> 1, k0 = ks & 1;
            const int dr = kl / 3, dc = kl - 3 * dr;
            const int cc = lk + 4 * k0;    // logical 16B chunk of the k-slice
            bf16x8 af[2], bv[2];
#pragma unroll
            for (int mf = 0; mf < 2; ++mf) {
                const int aaddr = kl * 8192 + (obase0 + mf * 16) * 128
                                + ((cc ^ (lm & 7)) << 4);
                af[mf] = *(const bf16x8*)(LDS + aaddr);
            }
            const int lpx = pxbase + dc;
#pragma unroll
            for (int nf = 0; nf < 2; ++nf) {
                const int slot = (s0 + nf + dr) & 7;
                const int baddr = RINGOFF + slot * SLOTB + lpx * 128
                                + ((cc ^ (lpx & 7)) << 4);
                bv[nf] = *(const bf16x8*)(LDS + baddr);
            }
#pragma unroll
            for (int mf = 0; mf < 2; ++mf)
#pragma unroll
                for (int nf = 0; nf < 2; ++nf)
                    acc[mf][nf] = __builtin_amdgcn_mfma_f32_16x16x32_bf16(
                        af[mf], bv[nf], acc[mf][nf], 0, 0, 0);
        }

        if (p < 15) WRITEPAIR(p + 2);      // vmcnt waits land here, then ds_write

        __syncthreads();                   // ring rotated; next pair visible

        // stores + acc reinit (overlap next phase's loads)
#pragma unroll
        for (int mf = 0; mf < 2; ++mf)
#pragma unroll
            for (int r = 0; r < 4; ++r) {
                const int o = oh * 32 + mf * 16 + lk * 4 + r;
#pragma unroll
                for (int nf = 0; nf < 2; ++nf) {
                    const int rowg = R0 + 2 * p + nf;
                    y[(((size_t)b * OO + o) * HH + rowg) * WW + ph * 64 + pxbase]
                        = acc[mf][nf][r];
                }
            }
#pragma unroll
        for (int mf = 0; mf < 2; ++mf)
#pragma unroll
            for (int nf = 0; nf < 2; ++nf)
#pragma unroll
                for (int r = 0; r < 4; ++r)
                    acc[mf][nf][r] = bbias[mf][r];

        s0 = (s0 + 2) & 7;
    }
}

extern "C" void kernel_launch(void* const* d_in, const int* in_sizes, int n_in,
                              void* d_out, int out_size, void* d_ws, size_t ws_size,
                              hipStream_t stream) {
    const float* addresses = (const float*)d_in[0];   // (B,O,I+1,F)
    const float* x         = (const float*)d_in[1];   // (B,I,H,W)
    const float* w_bank    = (const float*)d_in[2];   // (F,3,3)
    const float* b_bank    = (const float*)d_in[3];   // (F,)
    float* out = (float*)d_out;                       // (B,O,H,W)

    // ws layout: [bias 8KB][wT 2.25MB]
    float*  bias_ws = (float*)d_ws;
    __bf16* wT      = (__bf16*)((char*)d_ws + 8192);

    gen_weights<<<BB * OO, 64, 0, stream>>>(addresses, w_bank, b_bank, wT, bias_ws);
    conv_fused<<<256, 512, 0, stream>>>(x, wT, bias_ws, out);
}